// Round 13
// baseline (353.158 us; speedup 1.0000x reference)
//
#include <hip/hip_runtime.h>

// GAT 2-layer fused pipeline for MI355X.
// N=50000 nodes, E=800000 edges, H=4 heads, C=64 channels, D=4 att dims.
// Inputs bf16 (runtime-detected per-block, fp32 fallback); edge_index int32.
// Internal: bf16 MFMA node transforms, fp16 h matrix, fp32 accumulation.
//
// Round-13 vs round-12 (passed 336.3 us; k_aggr x2 pinned at 63 us = IF$
// random-line wall, 195MB @ ~3.4 TB/s):
//  - k_detect dropped: dtype probe inlined per-block (1 load + ballot).
//  - k_scatter: fill pre-seeded with rowptr in k_scan23 -> csr[atomicAdd] only
//    (removes 800k random rowptr gathers). No ws aliasing anywhere.
//  - k_nodeM: MFMA operand swap (A=W, B=x; fragment layouts identical so
//    Wb/Bsdf/LDS unchanged) -> D[row=outch, col=node]: 8B half4 h-stores
//    (was 2B) and float4 alpha stores. Same dot products, same rounding.
//  - k_aggr: exact r12/r10 version (proven).

#define N_NODES 50000
#define N_EDGES 800000
#define NB_SCAN 196   // ceil(N_NODES/256)

typedef _Float16 half4 __attribute__((ext_vector_type(4)));
typedef __attribute__((ext_vector_type(8))) short short8;     // 8 bf16
typedef __attribute__((ext_vector_type(4))) float f32x4;
typedef __attribute__((ext_vector_type(8))) unsigned short ushort8;

__device__ __forceinline__ float bf2f(unsigned short u){
  return __uint_as_float(((unsigned int)u) << 16);
}
__device__ __forceinline__ unsigned short f2bf(float f){
  unsigned int u = __float_as_uint(f);
  u = (u + 0x7FFFu + ((u >> 16) & 1u)) >> 16;   // round-to-nearest-even
  return (unsigned short)u;
}
__device__ __forceinline__ float ldf(const void* p, int i, bool bf){
  return bf ? bf2f(((const unsigned short*)p)[i]) : ((const float*)p)[i];
}

// Per-block dtype probe: low u16 of first 64 words of x. fp32 buffer -> low
// bits are mantissa (bf16-exponent plausible ~14%); bf16 buffer -> ~100%.
// Must be called pre-divergence (all lanes active).
__device__ __forceinline__ bool detect_bf(const unsigned int* __restrict__ xb, int tid){
  unsigned int w = xb[tid & 63] & 0xFFFFu;
  unsigned int e = (w >> 7) & 0xFFu;
  bool hit = (e >= 100u && e <= 135u);
  unsigned long long m = __ballot(hit);
  return __popcll(m) > 40;
}

// ---------------- fused setup ----------------
// W[Fx256] -> bf16 fragment layout (A- and B-fragment lane maps are identical):
// Wb[((nt*KT + kt)*64 + lane)*8 + j] = W[k = kt*32 + (lane>>4)*8 + j][n = nt*16 + (lane&15)]
// Bsd fragments: Bsdf[(kt*64 + lane)*8 + j] = Bsd[k][c=lane&15],
//   Bsd[k][c] = c<4 ? sum_d A[k,c*4+d]*attS[c*4+d]
//             : c<8 ? sum_d A[k,(c-4)*4+d]*attD[(c-4)*4+d] : 0
struct SetupPtrs {
  const void *W1, *A1, *aS1, *aD1, *b1, *W2, *A2, *aS2, *aD2, *b2;
};

__global__ __launch_bounds__(256) void k_setup(SetupPtrs S,
    const unsigned int* __restrict__ xb,
    int* __restrict__ deg,
    unsigned short* __restrict__ Wb1, unsigned short* __restrict__ Wb2,
    unsigned short* __restrict__ Bsd1f, unsigned short* __restrict__ Bsd2f,
    float* __restrict__ bc1, float* __restrict__ bc2)
{
  const int b = blockIdx.x, tid = threadIdx.x;
  const bool bf = detect_bf(xb, tid);
  if (b < 196){                                   // zero deg
    int i = b * 256 + tid;
    if (i < N_NODES) deg[i] = 0;
  } else if (b < 324){                            // wswz W1 (F=128, KT=4): 32768 elems
    int t = (b - 196) * 256 + tid;
    int j = t & 7, lane = (t >> 3) & 63, kt = (t >> 9) & 3, nt = t >> 11;
    int k = kt * 32 + (lane >> 4) * 8 + j;
    int n = nt * 16 + (lane & 15);
    Wb1[t] = bf ? ((const unsigned short*)S.W1)[k * 256 + n]
                : f2bf(((const float*)S.W1)[k * 256 + n]);
  } else if (b < 388){                            // wswz W2 (F=64, KT=2): 16384 elems
    int t = (b - 324) * 256 + tid;
    int j = t & 7, lane = (t >> 3) & 63, kt = (t >> 9) & 1, nt = t >> 10;
    int k = kt * 32 + (lane >> 4) * 8 + j;
    int n = nt * 16 + (lane & 15);
    Wb2[t] = bf ? ((const unsigned short*)S.W2)[k * 256 + n]
                : f2bf(((const float*)S.W2)[k * 256 + n]);
  } else if (b < 396){                            // Bsd1 fragments: 2048 elems (kt<4)
    int t = (b - 388) * 256 + tid;
    int j = t & 7, lane = (t >> 3) & 63, kt = t >> 9;
    int k = kt * 32 + (lane >> 4) * 8 + j;
    int c = lane & 15;
    float v = 0.f;
    if (c < 4){
      for (int dd = 0; dd < 4; ++dd)
        v += ldf(S.A1, k * 16 + c * 4 + dd, bf) * ldf(S.aS1, c * 4 + dd, bf);
    } else if (c < 8){
      int h = c - 4;
      for (int dd = 0; dd < 4; ++dd)
        v += ldf(S.A1, k * 16 + h * 4 + dd, bf) * ldf(S.aD1, h * 4 + dd, bf);
    }
    Bsd1f[t] = f2bf(v);
  } else if (b < 400){                            // Bsd2 fragments: 1024 elems (kt<2)
    int t = (b - 396) * 256 + tid;
    int j = t & 7, lane = (t >> 3) & 63, kt = t >> 9;
    int k = kt * 32 + (lane >> 4) * 8 + j;
    int c = lane & 15;
    float v = 0.f;
    if (c < 4){
      for (int dd = 0; dd < 4; ++dd)
        v += ldf(S.A2, k * 16 + c * 4 + dd, bf) * ldf(S.aS2, c * 4 + dd, bf);
    } else if (c < 8){
      int h = c - 4;
      for (int dd = 0; dd < 4; ++dd)
        v += ldf(S.A2, k * 16 + h * 4 + dd, bf) * ldf(S.aD2, h * 4 + dd, bf);
    }
    Bsd2f[t] = f2bf(v);
  } else {                                        // bias copies
    if (tid < 64)       bc1[tid] = ldf(S.b1, tid, bf);
    else if (tid < 128) bc2[tid - 64] = ldf(S.b2, tid - 64, bf);
  }
}

// ---------------- CSR build ----------------

__global__ __launch_bounds__(256) void k_hist(const int* __restrict__ dst,
                                              int* __restrict__ deg){
  int e = blockIdx.x * 256 + threadIdx.x;
  if (e < N_EDGES) atomicAdd(&deg[dst[e]], 1);
}

__global__ __launch_bounds__(256) void k_scan1(const int* __restrict__ deg,
                                               int* __restrict__ blocksum){
  int b = blockIdx.x, t = threadIdx.x, i = b * 256 + t;
  int v = (i < N_NODES) ? deg[i] : 0;
  for (int off = 1; off < 64; off <<= 1) v += __shfl_xor(v, off);
  __shared__ int sm[4];
  if ((t & 63) == 0) sm[t >> 6] = v;
  __syncthreads();
  if (t == 0) blocksum[b] = sm[0] + sm[1] + sm[2] + sm[3];
}

// fused scan2+scan3: each block locally scans the 196 blocksums, then its chunk.
// Also seeds fill[i] = rowptr[i] so scatter needs no rowptr gather.
__global__ __launch_bounds__(256) void k_scan23(const int* __restrict__ deg,
                                                const int* __restrict__ blocksum,
                                                int* __restrict__ rowptr,
                                                int* __restrict__ fill){
  __shared__ int sb[256];
  __shared__ int sm[256];
  int b = blockIdx.x, t = threadIdx.x, i = b * 256 + t;
  int vb = (t < NB_SCAN) ? blocksum[t] : 0;
  sb[t] = vb;
  int v = (i < N_NODES) ? deg[i] : 0;
  sm[t] = v;
  __syncthreads();
  for (int off = 1; off < 256; off <<= 1){
    int ub = (t >= off) ? sb[t - off] : 0;
    int um = (t >= off) ? sm[t - off] : 0;
    __syncthreads();
    sb[t] += ub; sm[t] += um;
    __syncthreads();
  }
  int blockoff = (b > 0) ? sb[b - 1] : 0;         // exclusive prefix of blocksums
  if (i < N_NODES){
    int rp = blockoff + sm[t] - v;
    rowptr[i] = rp;
    fill[i]   = rp;
  }
  if (i == 0) rowptr[N_NODES] = N_EDGES;
}

__global__ __launch_bounds__(256) void k_scatter(const int* __restrict__ src,
                                                 const int* __restrict__ dst,
                                                 int* __restrict__ fill,
                                                 int* __restrict__ csr_src){
  int e = blockIdx.x * 256 + threadIdx.x;
  if (e < N_EDGES){
    int pos = atomicAdd(&fill[dst[e]], 1);        // fill starts at rowptr[d]
    csr_src[pos] = src[e];
  }
}

// ---------------- node transform via MFMA (F = 128 or 64) ----------------
// block = 256 = 4 waves, 16 nodes/wave. A = W fragment, B = x fragment
// (identical lane maps) -> D[row=outch, col=node]: lane m = node, rows
// quad*4+r = 4 consecutive channels -> 8B half4 h-stores, float4 alpha stores.

template<int F, bool DYN>
__global__ __launch_bounds__(256) void k_nodeM(const void* __restrict__ xin_,
    const unsigned int* __restrict__ xb,
    const unsigned short* __restrict__ Wb, const unsigned short* __restrict__ Bsdf,
    _Float16* __restrict__ hmat, float* __restrict__ alpha_s, float* __restrict__ alpha_d)
{
  const int STR = F + 8;                   // row stride in ushorts (16B pad)
  const int KT  = F / 32;                  // K-tiles of 32
  const int CH  = F / 8;                   // ushort8 chunks per row
  __shared__ unsigned short xs[64 * (F + 8)];
  const int tid = threadIdx.x;
  const int base = blockIdx.x * 64;
  bool bf = true;
  if (DYN) bf = detect_bf(xb, tid);
  for (int v = tid; v < 64 * CH; v += 256){
    int row = v / CH, c8 = v % CH;
    int node = base + row; if (node >= N_NODES) node = N_NODES - 1;
    size_t g = (size_t)node * F + c8 * 8;
    ushort8 u;
    if (!DYN || bf){
      u = *(const ushort8*)((const unsigned short*)xin_ + g);
    } else {
      const float* xf = (const float*)xin_ + g;
      float4 f0 = *(const float4*)xf, f1 = *(const float4*)(xf + 4);
      u[0]=f2bf(f0.x); u[1]=f2bf(f0.y); u[2]=f2bf(f0.z); u[3]=f2bf(f0.w);
      u[4]=f2bf(f1.x); u[5]=f2bf(f1.y); u[6]=f2bf(f1.z); u[7]=f2bf(f1.w);
    }
    *(ushort8*)&xs[row * STR + c8 * 8] = u;
  }
  __syncthreads();

  const int wave = tid >> 6, l = tid & 63;
  const int quad = l >> 4, m = l & 15;
  const int wbase = base + wave * 16;
  const int node = wbase + m;              // this lane's node (D column)

  short8 xfrag[KT];                        // x as B-operand
  #pragma unroll
  for (int kt = 0; kt < KT; ++kt)
    xfrag[kt] = *(const short8*)&xs[(wave * 16 + m) * STR + kt * 32 + quad * 8];

  // alphas: D_a[row=c][col=node], c = quad*4+r. quad0 -> alpha_s, quad1 -> alpha_d.
  f32x4 aacc = (f32x4)0.f;
  #pragma unroll
  for (int kt = 0; kt < KT; ++kt){
    short8 sdfrag = *(const short8*)(Bsdf + ((size_t)kt * 64 + l) * 8);
    aacc = __builtin_amdgcn_mfma_f32_16x16x32_bf16(sdfrag, xfrag[kt], aacc, 0, 0, 0);
  }
  if (node < N_NODES){
    if (quad == 0)
      *(float4*)(alpha_s + node * 4) = make_float4(aacc[0], aacc[1], aacc[2], aacc[3]);
    else if (quad == 1)
      *(float4*)(alpha_d + node * 4) = make_float4(aacc[0], aacc[1], aacc[2], aacc[3]);
  }

  f32x4 acc[16];
  #pragma unroll
  for (int nt = 0; nt < 16; ++nt) acc[nt] = (f32x4)0.f;

  #pragma unroll
  for (int nt = 0; nt < 16; ++nt){
    #pragma unroll
    for (int kt = 0; kt < KT; ++kt){
      short8 wfrag = *(const short8*)(Wb + ((size_t)(nt * KT + kt) * 64 + l) * 8);
      acc[nt] = __builtin_amdgcn_mfma_f32_16x16x32_bf16(wfrag, xfrag[kt], acc[nt], 0, 0, 0);
    }
  }
  // D: row = outch = nt*16 + quad*4 + r, col = node -> 8B half4 per (nt)
  if (node < N_NODES){
    #pragma unroll
    for (int nt = 0; nt < 16; ++nt){
      half4 o;
      o.x = (_Float16)acc[nt][0]; o.y = (_Float16)acc[nt][1];
      o.z = (_Float16)acc[nt][2]; o.w = (_Float16)acc[nt][3];
      *(half4*)(hmat + (size_t)node * 256 + nt * 16 + quad * 4) = o;
    }
  }
}

// ---------------- aggregation (proven r10/r12 version) ----------------
// block = 256 = 4 waves, one wave per dst node. Lane l: head hh=l>>4, 4 channels.
// MODE 0: write x2 bf16 (internal). MODE 1: final output (probe: bf16 else fp32).

template<int MODE>
__global__ __launch_bounds__(256) void k_aggr(
    const _Float16* __restrict__ hmat, const float* __restrict__ alpha_s,
    const float* __restrict__ alpha_d, const int* __restrict__ rowptr,
    const int* __restrict__ csr_src, const float* __restrict__ bias,
    void* __restrict__ out, const unsigned int* __restrict__ xb)
{
  const int tid = threadIdx.x;
  bool bfout = true;
  if (MODE == 1) bfout = detect_bf(xb, tid);       // pre-divergence
  const int wave = tid >> 6, l = tid & 63;
  const int n = blockIdx.x * 4 + wave;
  const int hh = l >> 4;
  const float adv = alpha_d[n * 4 + hh];
  const int p0 = rowptr[n], p1 = rowptr[n + 1];
  const char* hb = (const char*)hmat + l * 8;      // lane base, 8B per half4
  const char* ab = (const char*)alpha_s + hh * 4;  // head base, 16B per node
  float4 acc = make_float4(0.f,0.f,0.f,0.f);
  float den = 0.f;
  int p = p0;
  int pa = (p0 + 3) & ~3; if (pa > p1) pa = p1;
  for (; p < pa; ++p){                             // head to 16B alignment
    int s = csr_src[p];
    float e = *(const float*)(ab + ((unsigned)s << 4)) + adv;
    e = fmaxf(e, 0.2f * e);
    float ex = __expf(e);
    half4 hv = *(const half4*)(hb + ((unsigned)s << 9));
    den += ex;
    acc.x += ex * (float)hv.x; acc.y += ex * (float)hv.y;
    acc.z += ex * (float)hv.z; acc.w += ex * (float)hv.w;
  }
  for (; p + 4 <= p1; p += 4){
    int4 s4 = *(const int4*)(csr_src + p);         // aligned 16B
    float a0 = *(const float*)(ab + ((unsigned)s4.x << 4));
    float a1 = *(const float*)(ab + ((unsigned)s4.y << 4));
    float a2 = *(const float*)(ab + ((unsigned)s4.z << 4));
    float a3 = *(const float*)(ab + ((unsigned)s4.w << 4));
    half4 h0 = *(const half4*)(hb + ((unsigned)s4.x << 9));
    half4 h1 = *(const half4*)(hb + ((unsigned)s4.y << 9));
    half4 h2 = *(const half4*)(hb + ((unsigned)s4.z << 9));
    half4 h3 = *(const half4*)(hb + ((unsigned)s4.w << 9));
    float e0 = a0 + adv; e0 = fmaxf(e0, 0.2f * e0);
    float e1 = a1 + adv; e1 = fmaxf(e1, 0.2f * e1);
    float e2 = a2 + adv; e2 = fmaxf(e2, 0.2f * e2);
    float e3 = a3 + adv; e3 = fmaxf(e3, 0.2f * e3);
    float ex0 = __expf(e0), ex1 = __expf(e1), ex2 = __expf(e2), ex3 = __expf(e3);
    den += (ex0 + ex1) + (ex2 + ex3);
    acc.x += ex0 * (float)h0.x + ex1 * (float)h1.x + ex2 * (float)h2.x + ex3 * (float)h3.x;
    acc.y += ex0 * (float)h0.y + ex1 * (float)h1.y + ex2 * (float)h2.y + ex3 * (float)h3.y;
    acc.z += ex0 * (float)h0.z + ex1 * (float)h1.z + ex2 * (float)h2.z + ex3 * (float)h3.z;
    acc.w += ex0 * (float)h0.w + ex1 * (float)h1.w + ex2 * (float)h2.w + ex3 * (float)h3.w;
  }
  for (; p < p1; ++p){                             // tail
    int s = csr_src[p];
    float e = *(const float*)(ab + ((unsigned)s << 4)) + adv;
    e = fmaxf(e, 0.2f * e);
    float ex = __expf(e);
    half4 hv = *(const half4*)(hb + ((unsigned)s << 9));
    den += ex;
    acc.x += ex * (float)hv.x; acc.y += ex * (float)hv.y;
    acc.z += ex * (float)hv.z; acc.w += ex * (float)hv.w;
  }
  float r = (den > 0.f) ? (1.f / den) : 0.f;
  acc.x *= r; acc.y *= r; acc.z *= r; acc.w *= r;
  acc.x += __shfl_xor(acc.x, 16); acc.y += __shfl_xor(acc.y, 16);
  acc.z += __shfl_xor(acc.z, 16); acc.w += __shfl_xor(acc.w, 16);
  acc.x += __shfl_xor(acc.x, 32); acc.y += __shfl_xor(acc.y, 32);
  acc.z += __shfl_xor(acc.z, 32); acc.w += __shfl_xor(acc.w, 32);
  if (l < 16){
    float vx = 0.25f * acc.x + bias[l * 4 + 0];
    float vy = 0.25f * acc.y + bias[l * 4 + 1];
    float vz = 0.25f * acc.z + bias[l * 4 + 2];
    float vw = 0.25f * acc.w + bias[l * 4 + 3];
    vx = fmaxf(vx, 0.1f * vx);                      // post-layer leaky 0.1
    vy = fmaxf(vy, 0.1f * vy);
    vz = fmaxf(vz, 0.1f * vz);
    vw = fmaxf(vw, 0.1f * vw);
    if (MODE == 0 || bfout){
      ushort4 o = make_ushort4(f2bf(vx), f2bf(vy), f2bf(vz), f2bf(vw));
      *(ushort4*)((unsigned short*)out + (size_t)n * 64 + l * 4) = o;
    } else {
      *(float4*)((float*)out + (size_t)n * 64 + l * 4) = make_float4(vx, vy, vz, vw);
    }
  }
}

// ---------------- launch ----------------

extern "C" void kernel_launch(void* const* d_in, const int* in_sizes, int n_in,
                              void* d_out, int out_size, void* d_ws, size_t ws_size,
                              hipStream_t stream)
{
  const void* x  = d_in[0];
  const unsigned int* xb = (const unsigned int*)d_in[0];
  const int* ei  = (const int*)d_in[1];
  const int* src = ei;
  const int* dst = ei + N_EDGES;

  char* ws = (char*)d_ws;                      // footprint ~69.7 MB (r12 layout, no aliasing)
  _Float16* hmat = (_Float16*)(ws);            // [N,256] fp16 (25.6 MB)
  unsigned short* Wb1 = (unsigned short*)(ws + 25600000);  // [32768] bf16 swizzled W1
  unsigned short* Wb2 = (unsigned short*)(ws + 25665536);  // [16384] bf16 swizzled W2
  unsigned short* x2  = (unsigned short*)(ws + 51200000);  // [N,64] bf16 layer-1 output
  float* as_    = (float*)(ws + 64000000);     // [N,4]
  float* ad_    = (float*)(ws + 64800000);     // [N,4]
  int*   deg    = (int*)  (ws + 65600000);     // [N]
  int*   fill   = (int*)  (ws + 65800000);     // [N]
  int*   rowptr = (int*)  (ws + 66000000);     // [N+1]
  int*   csr    = (int*)  (ws + 66200064);     // [E] src sorted by dst, 16B-aligned
  float* bc1    = (float*)(ws + 69539520);     // [64]
  float* bc2    = (float*)(ws + 69609536);     // [64]
  int*   bsum   = (int*)  (ws + 69609792);     // [256]
  unsigned short* Bsd1f = (unsigned short*)(ws + 69611840);  // [2048] bf16 fragments
  unsigned short* Bsd2f = (unsigned short*)(ws + 69615936);  // [1024] bf16 fragments

  SetupPtrs S;
  S.W1 = d_in[2];  S.A1 = d_in[3];  S.aS1 = d_in[4];  S.aD1 = d_in[5];  S.b1 = d_in[6];
  S.W2 = d_in[7];  S.A2 = d_in[8];  S.aS2 = d_in[9];  S.aD2 = d_in[10]; S.b2 = d_in[11];
  k_setup<<<401, 256, 0, stream>>>(S, xb, deg, Wb1, Wb2, Bsd1f, Bsd2f, bc1, bc2);

  k_hist   <<<(N_EDGES + 255) / 256, 256, 0, stream>>>(dst, deg);
  k_scan1  <<<NB_SCAN, 256, 0, stream>>>(deg, bsum);
  k_scan23 <<<NB_SCAN, 256, 0, stream>>>(deg, bsum, rowptr, fill);
  k_scatter<<<(N_EDGES + 255) / 256, 256, 0, stream>>>(src, dst, fill, csr);

  // layer 1 (Fin=128, dtype per probe)
  k_nodeM<128, true><<<(N_NODES + 63) / 64, 256, 0, stream>>>(x, xb, Wb1, Bsd1f, hmat, as_, ad_);
  k_aggr<0><<<N_NODES / 4, 256, 0, stream>>>(hmat, as_, ad_, rowptr, csr, bc1, x2, xb);
  // layer 2 (Fin=64, bf16 internal)
  k_nodeM<64, false><<<(N_NODES + 63) / 64, 256, 0, stream>>>(x2, nullptr, Wb2, Bsd2f, hmat, as_, ad_);
  k_aggr<1><<<N_NODES / 4, 256, 0, stream>>>(hmat, as_, ad_, rowptr, csr, bc2, d_out, xb);
}

// Round 14
// 325.954 us; speedup vs baseline: 1.0835x; 1.0835x over previous
//
#include <hip/hip_runtime.h>

// GAT 2-layer fused pipeline for MI355X.
// N=50000 nodes, E=800000 edges, H=4 heads, C=64 channels, D=4 att dims.
// Inputs bf16 (runtime-detected, fp32 fallback); edge_index int32.
// Internal: bf16 MFMA node transforms, fp16 h matrix, fp32 accumulation.
//
// Round-14 = round-12 source (proven 336.3 us; r13's 3-change bundle regressed
// to 353 and is fully reverted) + ONE change: block-partitioned fusion of
// independent kernels to overlap them on the serial stream:
//   - k_hist fused into k_setup (deg/fill zeroing -> one hipMemsetAsync).
//   - k_nodeM<128> fused into k_scatter's launch (independent: scatter needs
//     scan23, nodeM needs only setup outputs).
// Numerics bit-identical to r12 -> absmax 1.2207e-4 expected.

#define N_NODES 50000
#define N_EDGES 800000
#define NB_SCAN 196   // ceil(N_NODES/256)
#define NB_EDGE 3125  // N_EDGES/256

typedef _Float16 half4 __attribute__((ext_vector_type(4)));
typedef __attribute__((ext_vector_type(8))) short short8;     // 8 bf16
typedef __attribute__((ext_vector_type(4))) float f32x4;
typedef __attribute__((ext_vector_type(8))) unsigned short ushort8;

__device__ __forceinline__ float bf2f(unsigned short u){
  return __uint_as_float(((unsigned int)u) << 16);
}
__device__ __forceinline__ unsigned short f2bf(float f){
  unsigned int u = __float_as_uint(f);
  u = (u + 0x7FFFu + ((u >> 16) & 1u)) >> 16;   // round-to-nearest-even
  return (unsigned short)u;
}
__device__ __forceinline__ float ldf(const void* p, int i, bool bf){
  return bf ? bf2f(((const unsigned short*)p)[i]) : ((const float*)p)[i];
}

// ---------------- dtype probe (r12 form: one tiny kernel, flag in ws) ----------------
__global__ void k_detect(const unsigned int* __restrict__ xb, int* __restrict__ flag){
  int l = threadIdx.x;
  unsigned int w = xb[l] & 0xFFFFu;
  unsigned int e = (w >> 7) & 0xFFu;
  bool hit = (e >= 100u && e <= 135u);
  unsigned long long m = __ballot(hit);
  if (l == 0) *flag = (__popcll(m) > 40) ? 1 : 0;   // 1 = bf16 inputs
}

// ---------------- fused setup + hist ----------------
// Blocks 0..3124: edge histogram (deg pre-zeroed by hipMemsetAsync).
// Blocks 3125..3329: weight swizzles / Bsd prep / bias (r12 bodies).
// W[Fx256] -> bf16 B-fragment layout for mfma_f32_16x16x32_bf16:
// Wb[((nt*KT + kt)*64 + lane)*8 + j] = W[k = kt*32 + (lane>>4)*8 + j][n = nt*16 + (lane&15)]
// Bsd fragments: Bsdf[(kt*64 + lane)*8 + j] = Bsd[k][c=lane&15],
//   Bsd[k][c] = c<4 ? sum_d A[k,c*4+d]*attS[c*4+d]
//             : c<8 ? sum_d A[k,(c-4)*4+d]*attD[(c-4)*4+d] : 0
struct SetupPtrs {
  const void *W1, *A1, *aS1, *aD1, *b1, *W2, *A2, *aS2, *aD2, *b2;
};

__global__ __launch_bounds__(256) void k_setup_hist(SetupPtrs S,
    const int* __restrict__ dst, int* __restrict__ deg,
    unsigned short* __restrict__ Wb1, unsigned short* __restrict__ Wb2,
    unsigned short* __restrict__ Bsd1f, unsigned short* __restrict__ Bsd2f,
    float* __restrict__ bc1, float* __restrict__ bc2,
    const int* __restrict__ flag)
{
  const int b = blockIdx.x, tid = threadIdx.x;
  if (b < NB_EDGE){                               // histogram
    int e = b * 256 + tid;
    if (e < N_EDGES) atomicAdd(&deg[dst[e]], 1);
    return;
  }
  const bool bf = (*flag != 0);
  const int bw = b - NB_EDGE;                     // 0..204 weight-work blocks
  if (bw < 128){                                  // wswz W1 (F=128, KT=4): 32768 elems
    int t = bw * 256 + tid;
    int j = t & 7, lane = (t >> 3) & 63, kt = (t >> 9) & 3, nt = t >> 11;
    int k = kt * 32 + (lane >> 4) * 8 + j;
    int n = nt * 16 + (lane & 15);
    Wb1[t] = bf ? ((const unsigned short*)S.W1)[k * 256 + n]
                : f2bf(((const float*)S.W1)[k * 256 + n]);
  } else if (bw < 192){                           // wswz W2 (F=64, KT=2): 16384 elems
    int t = (bw - 128) * 256 + tid;
    int j = t & 7, lane = (t >> 3) & 63, kt = (t >> 9) & 1, nt = t >> 10;
    int k = kt * 32 + (lane >> 4) * 8 + j;
    int n = nt * 16 + (lane & 15);
    Wb2[t] = bf ? ((const unsigned short*)S.W2)[k * 256 + n]
                : f2bf(((const float*)S.W2)[k * 256 + n]);
  } else if (bw < 200){                           // Bsd1 fragments: 2048 elems (kt<4)
    int t = (bw - 192) * 256 + tid;
    int j = t & 7, lane = (t >> 3) & 63, kt = t >> 9;
    int k = kt * 32 + (lane >> 4) * 8 + j;
    int c = lane & 15;
    float v = 0.f;
    if (c < 4){
      for (int dd = 0; dd < 4; ++dd)
        v += ldf(S.A1, k * 16 + c * 4 + dd, bf) * ldf(S.aS1, c * 4 + dd, bf);
    } else if (c < 8){
      int h = c - 4;
      for (int dd = 0; dd < 4; ++dd)
        v += ldf(S.A1, k * 16 + h * 4 + dd, bf) * ldf(S.aD1, h * 4 + dd, bf);
    }
    Bsd1f[t] = f2bf(v);
  } else if (bw < 204){                           // Bsd2 fragments: 1024 elems (kt<2)
    int t = (bw - 200) * 256 + tid;
    int j = t & 7, lane = (t >> 3) & 63, kt = t >> 9;
    int k = kt * 32 + (lane >> 4) * 8 + j;
    int c = lane & 15;
    float v = 0.f;
    if (c < 4){
      for (int dd = 0; dd < 4; ++dd)
        v += ldf(S.A2, k * 16 + c * 4 + dd, bf) * ldf(S.aS2, c * 4 + dd, bf);
    } else if (c < 8){
      int h = c - 4;
      for (int dd = 0; dd < 4; ++dd)
        v += ldf(S.A2, k * 16 + h * 4 + dd, bf) * ldf(S.aD2, h * 4 + dd, bf);
    }
    Bsd2f[t] = f2bf(v);
  } else {                                        // bias copies
    if (tid < 64)       bc1[tid] = ldf(S.b1, tid, bf);
    else if (tid < 128) bc2[tid - 64] = ldf(S.b2, tid - 64, bf);
  }
}

// ---------------- CSR scans (r12 bodies) ----------------

__global__ __launch_bounds__(256) void k_scan1(const int* __restrict__ deg,
                                               int* __restrict__ blocksum){
  int b = blockIdx.x, t = threadIdx.x, i = b * 256 + t;
  int v = (i < N_NODES) ? deg[i] : 0;
  for (int off = 1; off < 64; off <<= 1) v += __shfl_xor(v, off);
  __shared__ int sm[4];
  if ((t & 63) == 0) sm[t >> 6] = v;
  __syncthreads();
  if (t == 0) blocksum[b] = sm[0] + sm[1] + sm[2] + sm[3];
}

// fused scan2+scan3: each block locally scans the 196 blocksums, then its chunk
__global__ __launch_bounds__(256) void k_scan23(const int* __restrict__ deg,
                                                const int* __restrict__ blocksum,
                                                int* __restrict__ rowptr){
  __shared__ int sb[256];
  __shared__ int sm[256];
  int b = blockIdx.x, t = threadIdx.x, i = b * 256 + t;
  int vb = (t < NB_SCAN) ? blocksum[t] : 0;
  sb[t] = vb;
  int v = (i < N_NODES) ? deg[i] : 0;
  sm[t] = v;
  __syncthreads();
  for (int off = 1; off < 256; off <<= 1){
    int ub = (t >= off) ? sb[t - off] : 0;
    int um = (t >= off) ? sm[t - off] : 0;
    __syncthreads();
    sb[t] += ub; sm[t] += um;
    __syncthreads();
  }
  int blockoff = (b > 0) ? sb[b - 1] : 0;         // exclusive prefix of blocksums
  if (i < N_NODES) rowptr[i] = blockoff + sm[t] - v;
  if (i == 0) rowptr[N_NODES] = N_EDGES;
}

// ---------------- fused scatter + layer-1 nodeM ----------------
// Blocks 0..3124: CSR scatter (r12 body: rowptr gather + atomic fill).
// Blocks 3125..3906: k_nodeM<128> (r12 body) — independent of scatter, runs
// concurrently in the same launch slot.

template<int F, bool DYN>
__device__ __forceinline__ void nodeM_body(int nblk, int tid,
    const void* __restrict__ xin_,
    const unsigned short* __restrict__ Wb, const unsigned short* __restrict__ Bsdf,
    _Float16* __restrict__ hmat, float* __restrict__ alpha_s, float* __restrict__ alpha_d,
    const int* __restrict__ flag)
{
  const int STR = F + 8;                   // row stride in ushorts (16B pad)
  const int KT  = F / 32;                  // K-tiles of 32
  const int CH  = F / 8;                   // ushort8 chunks per row
  __shared__ unsigned short xs[64 * (F + 8)];
  const int base = nblk * 64;
  bool bf = true;
  if (DYN) bf = (*flag != 0);
  for (int v = tid; v < 64 * CH; v += 256){
    int row = v / CH, c8 = v % CH;
    int node = base + row; if (node >= N_NODES) node = N_NODES - 1;
    size_t g = (size_t)node * F + c8 * 8;
    ushort8 u;
    if (!DYN || bf){
      u = *(const ushort8*)((const unsigned short*)xin_ + g);
    } else {
      const float* xf = (const float*)xin_ + g;
      float4 f0 = *(const float4*)xf, f1 = *(const float4*)(xf + 4);
      u[0]=f2bf(f0.x); u[1]=f2bf(f0.y); u[2]=f2bf(f0.z); u[3]=f2bf(f0.w);
      u[4]=f2bf(f1.x); u[5]=f2bf(f1.y); u[6]=f2bf(f1.z); u[7]=f2bf(f1.w);
    }
    *(ushort8*)&xs[row * STR + c8 * 8] = u;
  }
  __syncthreads();

  const int wave = tid >> 6, l = tid & 63;
  const int quad = l >> 4, m = l & 15;
  const int wbase = base + wave * 16;

  short8 afrag[KT];
  #pragma unroll
  for (int kt = 0; kt < KT; ++kt)
    afrag[kt] = *(const short8*)&xs[(wave * 16 + m) * STR + kt * 32 + quad * 8];

  // alphas: aacc[M][c] = sum_k x[M][k] * Bsd[k][c]
  f32x4 aacc = (f32x4)0.f;
  #pragma unroll
  for (int kt = 0; kt < KT; ++kt){
    short8 sdfrag = *(const short8*)(Bsdf + ((size_t)kt * 64 + l) * 8);
    aacc = __builtin_amdgcn_mfma_f32_16x16x32_bf16(afrag[kt], sdfrag, aacc, 0, 0, 0);
  }
  if (m < 8){
    float* dstp = (m < 4) ? alpha_s : alpha_d;
    int hh = m & 3;
    #pragma unroll
    for (int r = 0; r < 4; ++r){
      int node = wbase + quad * 4 + r;
      if (node < N_NODES) dstp[node * 4 + hh] = aacc[r];
    }
  }

  f32x4 acc[16];
  #pragma unroll
  for (int nt = 0; nt < 16; ++nt) acc[nt] = (f32x4)0.f;

  #pragma unroll
  for (int nt = 0; nt < 16; ++nt){
    #pragma unroll
    for (int kt = 0; kt < KT; ++kt){
      short8 bfrag = *(const short8*)(Wb + ((size_t)(nt * KT + kt) * 64 + l) * 8);
      acc[nt] = __builtin_amdgcn_mfma_f32_16x16x32_bf16(afrag[kt], bfrag, acc[nt], 0, 0, 0);
    }
  }
  // C/D: col = nt*16 + m, node = wbase + quad*4 + r
  #pragma unroll
  for (int r = 0; r < 4; ++r){
    int node = wbase + quad * 4 + r;
    if (node < N_NODES){
      #pragma unroll
      for (int nt = 0; nt < 16; ++nt)
        hmat[(size_t)node * 256 + nt * 16 + m] = (_Float16)acc[nt][r];
    }
  }
}

__global__ __launch_bounds__(256) void k_scatter_node1(
    const int* __restrict__ src, const int* __restrict__ dst,
    const int* __restrict__ rowptr, int* __restrict__ fill,
    int* __restrict__ csr_src,
    const void* __restrict__ xin_,
    const unsigned short* __restrict__ Wb, const unsigned short* __restrict__ Bsdf,
    _Float16* __restrict__ hmat, float* __restrict__ alpha_s, float* __restrict__ alpha_d,
    const int* __restrict__ flag)
{
  const int b = blockIdx.x, tid = threadIdx.x;
  if (b < NB_EDGE){                               // scatter
    int e = b * 256 + tid;
    if (e < N_EDGES){
      int d = dst[e];
      int pos = rowptr[d] + atomicAdd(&fill[d], 1);
      csr_src[pos] = src[e];
    }
    return;
  }
  nodeM_body<128, true>(b - NB_EDGE, tid, xin_, Wb, Bsdf, hmat, alpha_s, alpha_d, flag);
}

// standalone layer-2 node kernel (r12 body)
template<int F, bool DYN>
__global__ __launch_bounds__(256) void k_nodeM(const void* __restrict__ xin_,
    const unsigned short* __restrict__ Wb, const unsigned short* __restrict__ Bsdf,
    _Float16* __restrict__ hmat, float* __restrict__ alpha_s, float* __restrict__ alpha_d,
    const int* __restrict__ flag)
{
  nodeM_body<F, DYN>(blockIdx.x, threadIdx.x, xin_, Wb, Bsdf, hmat, alpha_s, alpha_d, flag);
}

// ---------------- aggregation (proven r10/r12 version) ----------------
// block = 256 = 4 waves, one wave per dst node. Lane l: head hh=l>>4, 4 channels.
// MODE 0: write x2 bf16 (internal). MODE 1: final output (flag: bf16 else fp32).

template<int MODE>
__global__ __launch_bounds__(256) void k_aggr(
    const _Float16* __restrict__ hmat, const float* __restrict__ alpha_s,
    const float* __restrict__ alpha_d, const int* __restrict__ rowptr,
    const int* __restrict__ csr_src, const float* __restrict__ bias,
    void* __restrict__ out, const int* __restrict__ flag)
{
  const int tid = threadIdx.x;
  const int wave = tid >> 6, l = tid & 63;
  const int n = blockIdx.x * 4 + wave;
  const int hh = l >> 4;
  const float adv = alpha_d[n * 4 + hh];
  const int p0 = rowptr[n], p1 = rowptr[n + 1];
  const char* hb = (const char*)hmat + l * 8;          // lane base, 8B per half4
  const char* ab = (const char*)alpha_s + hh * 4;      // head base, 16B per node
  float4 acc = make_float4(0.f,0.f,0.f,0.f);
  float den = 0.f;
  int p = p0;
  int pa = (p0 + 3) & ~3; if (pa > p1) pa = p1;
  for (; p < pa; ++p){                                 // head to 16B alignment
    int s = csr_src[p];
    float e = *(const float*)(ab + ((unsigned)s << 4)) + adv;
    e = fmaxf(e, 0.2f * e);
    float ex = __expf(e);
    half4 hv = *(const half4*)(hb + ((unsigned)s << 9));
    den += ex;
    acc.x += ex * (float)hv.x; acc.y += ex * (float)hv.y;
    acc.z += ex * (float)hv.z; acc.w += ex * (float)hv.w;
  }
  for (; p + 4 <= p1; p += 4){
    int4 s4 = *(const int4*)(csr_src + p);             // aligned 16B
    float a0 = *(const float*)(ab + ((unsigned)s4.x << 4));
    float a1 = *(const float*)(ab + ((unsigned)s4.y << 4));
    float a2 = *(const float*)(ab + ((unsigned)s4.z << 4));
    float a3 = *(const float*)(ab + ((unsigned)s4.w << 4));
    half4 h0 = *(const half4*)(hb + ((unsigned)s4.x << 9));
    half4 h1 = *(const half4*)(hb + ((unsigned)s4.y << 9));
    half4 h2 = *(const half4*)(hb + ((unsigned)s4.z << 9));
    half4 h3 = *(const half4*)(hb + ((unsigned)s4.w << 9));
    float e0 = a0 + adv; e0 = fmaxf(e0, 0.2f * e0);
    float e1 = a1 + adv; e1 = fmaxf(e1, 0.2f * e1);
    float e2 = a2 + adv; e2 = fmaxf(e2, 0.2f * e2);
    float e3 = a3 + adv; e3 = fmaxf(e3, 0.2f * e3);
    float ex0 = __expf(e0), ex1 = __expf(e1), ex2 = __expf(e2), ex3 = __expf(e3);
    den += (ex0 + ex1) + (ex2 + ex3);
    acc.x += ex0 * (float)h0.x + ex1 * (float)h1.x + ex2 * (float)h2.x + ex3 * (float)h3.x;
    acc.y += ex0 * (float)h0.y + ex1 * (float)h1.y + ex2 * (float)h2.y + ex3 * (float)h3.y;
    acc.z += ex0 * (float)h0.z + ex1 * (float)h1.z + ex2 * (float)h2.z + ex3 * (float)h3.z;
    acc.w += ex0 * (float)h0.w + ex1 * (float)h1.w + ex2 * (float)h2.w + ex3 * (float)h3.w;
  }
  for (; p < p1; ++p){                                 // tail
    int s = csr_src[p];
    float e = *(const float*)(ab + ((unsigned)s << 4)) + adv;
    e = fmaxf(e, 0.2f * e);
    float ex = __expf(e);
    half4 hv = *(const half4*)(hb + ((unsigned)s << 9));
    den += ex;
    acc.x += ex * (float)hv.x; acc.y += ex * (float)hv.y;
    acc.z += ex * (float)hv.z; acc.w += ex * (float)hv.w;
  }
  float r = (den > 0.f) ? (1.f / den) : 0.f;
  acc.x *= r; acc.y *= r; acc.z *= r; acc.w *= r;
  acc.x += __shfl_xor(acc.x, 16); acc.y += __shfl_xor(acc.y, 16);
  acc.z += __shfl_xor(acc.z, 16); acc.w += __shfl_xor(acc.w, 16);
  acc.x += __shfl_xor(acc.x, 32); acc.y += __shfl_xor(acc.y, 32);
  acc.z += __shfl_xor(acc.z, 32); acc.w += __shfl_xor(acc.w, 32);
  if (l < 16){
    float vx = 0.25f * acc.x + bias[l * 4 + 0];
    float vy = 0.25f * acc.y + bias[l * 4 + 1];
    float vz = 0.25f * acc.z + bias[l * 4 + 2];
    float vw = 0.25f * acc.w + bias[l * 4 + 3];
    vx = fmaxf(vx, 0.1f * vx);                          // post-layer leaky 0.1
    vy = fmaxf(vy, 0.1f * vy);
    vz = fmaxf(vz, 0.1f * vz);
    vw = fmaxf(vw, 0.1f * vw);
    if (MODE == 0){
      ushort4 o = make_ushort4(f2bf(vx), f2bf(vy), f2bf(vz), f2bf(vw));
      *(ushort4*)((unsigned short*)out + (size_t)n * 64 + l * 4) = o;   // x2 bf16
    } else {
      if (*flag){
        ushort4 o = make_ushort4(f2bf(vx), f2bf(vy), f2bf(vz), f2bf(vw));
        *(ushort4*)((unsigned short*)out + (size_t)n * 64 + l * 4) = o;
      } else {
        *(float4*)((float*)out + (size_t)n * 64 + l * 4) = make_float4(vx, vy, vz, vw);
      }
    }
  }
}

// ---------------- launch ----------------

extern "C" void kernel_launch(void* const* d_in, const int* in_sizes, int n_in,
                              void* d_out, int out_size, void* d_ws, size_t ws_size,
                              hipStream_t stream)
{
  const void* x  = d_in[0];
  const int* ei  = (const int*)d_in[1];
  const int* src = ei;
  const int* dst = ei + N_EDGES;

  char* ws = (char*)d_ws;                      // footprint ~69.7 MB (r12 layout, no aliasing)
  _Float16* hmat = (_Float16*)(ws);            // [N,256] fp16 (25.6 MB)
  unsigned short* Wb1 = (unsigned short*)(ws + 25600000);  // [32768] bf16 swizzled W1
  unsigned short* Wb2 = (unsigned short*)(ws + 25665536);  // [16384] bf16 swizzled W2
  unsigned short* x2  = (unsigned short*)(ws + 51200000);  // [N,64] bf16 layer-1 output
  float* as_    = (float*)(ws + 64000000);     // [N,4]
  float* ad_    = (float*)(ws + 64800000);     // [N,4]
  int*   deg    = (int*)  (ws + 65600000);     // [N]   (deg+fill contiguous for 1 memset)
  int*   fill   = (int*)  (ws + 65800000);     // [N]
  int*   rowptr = (int*)  (ws + 66000000);     // [N+1]
  int*   csr    = (int*)  (ws + 66200064);     // [E] src sorted by dst, 16B-aligned
  int*   flag   = (int*)  (ws + 69400064);     // dtype flag (1 = bf16)
  float* bc1    = (float*)(ws + 69539520);     // [64]
  float* bc2    = (float*)(ws + 69609536);     // [64]
  int*   bsum   = (int*)  (ws + 69609792);     // [256]
  unsigned short* Bsd1f = (unsigned short*)(ws + 69611840);  // [2048] bf16 fragments
  unsigned short* Bsd2f = (unsigned short*)(ws + 69615936);  // [1024] bf16 fragments

  k_detect<<<1, 64, 0, stream>>>((const unsigned int*)x, flag);
  hipMemsetAsync(deg, 0, 2 * N_NODES * sizeof(int), stream);   // deg + fill (contiguous)

  SetupPtrs S;
  S.W1 = d_in[2];  S.A1 = d_in[3];  S.aS1 = d_in[4];  S.aD1 = d_in[5];  S.b1 = d_in[6];
  S.W2 = d_in[7];  S.A2 = d_in[8];  S.aS2 = d_in[9];  S.aD2 = d_in[10]; S.b2 = d_in[11];
  // hist (3125 blocks) || weight-prep (205 blocks)
  k_setup_hist<<<NB_EDGE + 205, 256, 0, stream>>>(S, dst, deg, Wb1, Wb2,
                                                  Bsd1f, Bsd2f, bc1, bc2, flag);

  k_scan1 <<<NB_SCAN, 256, 0, stream>>>(deg, bsum);
  k_scan23<<<NB_SCAN, 256, 0, stream>>>(deg, bsum, rowptr);

  // scatter (3125 blocks) || layer-1 nodeM (782 blocks)
  k_scatter_node1<<<NB_EDGE + (N_NODES + 63) / 64, 256, 0, stream>>>(
      src, dst, rowptr, fill, csr, x, Wb1, Bsd1f, hmat, as_, ad_, flag);

  k_aggr<0><<<N_NODES / 4, 256, 0, stream>>>(hmat, as_, ad_, rowptr, csr, bc1, x2, flag);
  // layer 2 (Fin=64, bf16 internal)
  k_nodeM<64, false><<<(N_NODES + 63) / 64, 256, 0, stream>>>(x2, Wb2, Bsd2f, hmat, as_, ad_, flag);
  k_aggr<1><<<N_NODES / 4, 256, 0, stream>>>(hmat, as_, ad_, rowptr, csr, bc2, d_out, flag);
}